// Round 1
// baseline (172.845 us; speedup 1.0000x reference)
//
#include <hip/hip_runtime.h>

#define BB 4
#define CC 64
#define HH 128
#define WW 128
#define OO 64
#define HWs (HH*WW)

// Pre-transpose deform_w (O,C,3,3) -> wt[k][c][o] so per-tap LDS staging is coalesced.
__global__ void transpose_w(const float* __restrict__ dw, float* __restrict__ wt) {
    int t = blockIdx.x * 256 + threadIdx.x;          // t = (k*64 + c)*64 + o
    if (t >= OO * CC * 9) return;
    int o = t & 63;
    int c = (t >> 6) & 63;
    int k = t >> 12;
    wt[t] = dw[(o * CC + c) * 9 + k];
}

__global__ __launch_bounds__(256) void deform_kernel(
    const float* __restrict__ x,
    const float* __restrict__ offw,
    const float* __restrict__ offb,
    const float* __restrict__ dw,
    const float* __restrict__ dbias,
    const float* __restrict__ wt,
    int use_wt,
    float* __restrict__ out)
{
    __shared__ float offs[18][128];     // offset channels for this row
    __shared__ float samp[CC][128];     // bilinear samples, one tap at a time
    __shared__ float wlds[CC][68];      // W_k[c][o], padded to 68 floats

    const int tid = threadIdx.x;
    const int bid = blockIdx.x;          // 0..511
    const int row = bid & 127;
    const int b   = bid >> 7;
    const float* xb0 = x + (size_t)b * CC * HWs;

    // ---------------- Phase 1: offset conv (18 ch) for this row ----------------
    {
        const int wv  = tid >> 6;                       // wave id 0..3
        const int ln1 = tid & 63;
        const int col = ln1 + ((wv & 1) << 6);          // 0..127
        const int chb = __builtin_amdgcn_readfirstlane((wv >> 1) * 9); // 0 or 9

        float acc9[9];
        #pragma unroll
        for (int j = 0; j < 9; ++j) acc9[j] = offb[chb + j];

        const bool rok0 = (row > 0), rok2 = (row < HH - 1);
        const bool cok0 = (col > 0), cok2 = (col < WW - 1);
        const int r0 = (row - 1) * WW, r1 = row * WW, r2 = (row + 1) * WW;

        for (int c = 0; c < CC; ++c) {
            const float* xc = xb0 + c * HWs;
            float xv[9];
            xv[0] = (rok0 & cok0) ? xc[r0 + col - 1] : 0.f;
            xv[1] =  rok0         ? xc[r0 + col    ] : 0.f;
            xv[2] = (rok0 & cok2) ? xc[r0 + col + 1] : 0.f;
            xv[3] =  cok0         ? xc[r1 + col - 1] : 0.f;
            xv[4] =                 xc[r1 + col    ];
            xv[5] =  cok2         ? xc[r1 + col + 1] : 0.f;
            xv[6] = (rok2 & cok0) ? xc[r2 + col - 1] : 0.f;
            xv[7] =  rok2         ? xc[r2 + col    ] : 0.f;
            xv[8] = (rok2 & cok2) ? xc[r2 + col + 1] : 0.f;

            const float* wp = offw + (size_t)chb * (CC * 9) + c * 9;
            #pragma unroll
            for (int j = 0; j < 9; ++j) {
                #pragma unroll
                for (int kk = 0; kk < 9; ++kk)
                    acc9[j] = fmaf(xv[kk], wp[j * (CC * 9) + kk], acc9[j]);
            }
        }
        #pragma unroll
        for (int j = 0; j < 9; ++j) offs[chb + j][col] = acc9[j];
    }
    __syncthreads();

    // ---------------- Tap loop ----------------
    const int ln    = tid & 63;           // pixel lane for matmul (and +64)
    const int obase = (tid >> 6) * 16;    // 16 output channels per thread
    const int gpx   = tid & 127;          // gather pixel
    const int gc0   = tid >> 7;           // gather channel parity

    float acc0[16], acc1[16];
    #pragma unroll
    for (int j = 0; j < 16; ++j) { acc0[j] = 0.f; acc1[j] = 0.f; }

    for (int k = 0; k < 9; ++k) {
        // ---- stage W_k[c][o] into LDS ----
        if (use_wt) {
            const float* s = wt + k * (CC * OO);
            #pragma unroll
            for (int i = 0; i < 16; ++i) {
                int e = tid + i * 256;            // e = c*64 + o
                wlds[e >> 6][e & 63] = s[e];
            }
        } else {
            #pragma unroll
            for (int i = 0; i < 16; ++i) {
                int e = tid + i * 256;            // o = e>>6, c = e&63
                wlds[e & 63][e >> 6] = dw[((e >> 6) * CC + (e & 63)) * 9 + k];
            }
        }

        // ---- per-pixel bilinear parameters ----
        const float dy = offs[2 * k    ][gpx];
        const float dx = offs[2 * k + 1][gpx];
        const float py  = (float)(row - 1 + k / 3) + dy;
        const float pxf = (float)(gpx - 1 + k % 3) + dx;
        const float y0f = floorf(py), x0f = floorf(pxf);
        const float wy = py - y0f, wx = pxf - x0f;
        const int y0 = (int)y0f, x0 = (int)x0f;
        const int y1 = y0 + 1,  x1 = x0 + 1;
        const bool vy0 = (y0 >= 0) & (y0 < HH);
        const bool vy1 = (y1 >= 0) & (y1 < HH);
        const bool vx0 = (x0 >= 0) & (x0 < WW);
        const bool vx1 = (x1 >= 0) & (x1 < WW);
        const float w00 = (1.f - wy) * (1.f - wx) * (float)(vy0 & vx0);
        const float w01 = (1.f - wy) * wx         * (float)(vy0 & vx1);
        const float w10 = wy * (1.f - wx)         * (float)(vy1 & vx0);
        const float w11 = wy * wx                 * (float)(vy1 & vx1);
        const int cy0 = min(max(y0, 0), HH - 1), cy1 = min(max(y1, 0), HH - 1);
        const int cx0 = min(max(x0, 0), WW - 1), cx1 = min(max(x1, 0), WW - 1);
        const int a00 = cy0 * WW + cx0, a01 = cy0 * WW + cx1;
        const int a10 = cy1 * WW + cx0, a11 = cy1 * WW + cx1;

        // ---- gather 32 channels for this pixel ----
        const float* xc = xb0 + gc0 * HWs;
        #pragma unroll 8
        for (int cc = 0; cc < 32; ++cc) {
            const float* p = xc + (size_t)(cc * 2) * HWs;
            float v = w00 * p[a00] + w01 * p[a01] + w10 * p[a10] + w11 * p[a11];
            samp[gc0 + 2 * cc][gpx] = v;
        }
        __syncthreads();

        // ---- matmul: out[o][p] += W_k[c][o] * samp[c][p] ----
        #pragma unroll 4
        for (int c = 0; c < CC; ++c) {
            const float s0 = samp[c][ln];
            const float s1 = samp[c][ln + 64];
            const float4* wr = (const float4*)&wlds[c][obase];
            float wv16[16];
            *(float4*)&wv16[0]  = wr[0];
            *(float4*)&wv16[4]  = wr[1];
            *(float4*)&wv16[8]  = wr[2];
            *(float4*)&wv16[12] = wr[3];
            #pragma unroll
            for (int j = 0; j < 16; ++j) {
                acc0[j] = fmaf(wv16[j], s0, acc0[j]);
                acc1[j] = fmaf(wv16[j], s1, acc1[j]);
            }
        }
        __syncthreads();
    }

    // ---------------- Epilogue ----------------
    #pragma unroll
    for (int j = 0; j < 16; ++j) {
        const float bias = dbias[obase + j];
        float* op = out + ((size_t)(b * OO + obase + j) * HH + row) * WW;
        op[ln]      = acc0[j] + bias;
        op[ln + 64] = acc1[j] + bias;
    }
}

extern "C" void kernel_launch(void* const* d_in, const int* in_sizes, int n_in,
                              void* d_out, int out_size, void* d_ws, size_t ws_size,
                              hipStream_t stream) {
    const float* x     = (const float*)d_in[0];
    const float* offw  = (const float*)d_in[1];
    const float* offb  = (const float*)d_in[2];
    const float* dw    = (const float*)d_in[3];
    const float* dbias = (const float*)d_in[4];
    float* out = (float*)d_out;
    float* wtp = (float*)d_ws;

    const int use_wt = (ws_size >= (size_t)(OO * CC * 9 * sizeof(float))) ? 1 : 0;
    if (use_wt) {
        transpose_w<<<(OO * CC * 9 + 255) / 256, 256, 0, stream>>>(dw, wtp);
    }
    deform_kernel<<<BB * HH, 256, 0, stream>>>(x, offw, offb, dw, dbias, wtp, use_wt, out);
}

// Round 2
// 66.528 us; speedup vs baseline: 2.5981x; 2.5981x over previous
//
#include <hip/hip_runtime.h>
#include <hip/hip_fp16.h>

#define BB 4
#define CC 64
#define HH 128
#define WW 128
#define OO 64
#define HWs (HH*WW)

typedef _Float16 f16;
typedef _Float16 f16x8 __attribute__((ext_vector_type(8)));
typedef float f32x4 __attribute__((ext_vector_type(4)));

// ---------------- prep 1: x (B,C,H,W) f32 -> x_t (B,H,W,C) f16 ----------------
__global__ __launch_bounds__(128) void transpose_x(const float* __restrict__ x,
                                                   f16* __restrict__ xt) {
    const int b  = blockIdx.x >> 7;
    const int y  = blockIdx.x & 127;
    const int px = threadIdx.x;
    const float* src = x + (size_t)b * CC * HWs + y * WW + px;
    f16* dst = xt + (((size_t)b * HH + y) * WW + px) * CC;
    #pragma unroll
    for (int cg = 0; cg < 8; ++cg) {
        f16x8 t8;
        #pragma unroll
        for (int j = 0; j < 8; ++j)
            t8[j] = (f16)src[(size_t)(cg * 8 + j) * HWs];
        *(f16x8*)(dst + cg * 8) = t8;
    }
}

// ---------------- prep 2: weights -> MFMA A-fragment layout (f16) ----------------
// wA_off[idx=ks*2+mt][lane][8]  : A[m=o pad32][k=tap*64+c], ks=0..17 (K=32 steps)
// wA_def[idx=(tap*2+ks)*4+mt][lane][8] : per-tap A[m=o 64][k=c 64], ks = c-half
__global__ __launch_bounds__(256) void prep_w(const float* __restrict__ offw,
                                              const float* __restrict__ dw,
                                              f16* __restrict__ wA_off,
                                              f16* __restrict__ wA_def) {
    const int t = blockIdx.x * 256 + threadIdx.x;
    const int l = t & 63;
    const int idx = t >> 6;
    f16x8 v;
    if (idx < 36) {
        const int mt = idx & 1, ks = idx >> 1;
        const int o = mt * 16 + (l & 15);
        const int tap = ks >> 1, ky = tap / 3, kx = tap % 3;
        #pragma unroll
        for (int i = 0; i < 8; ++i) {
            const int c = (ks & 1) * 32 + (l >> 4) * 8 + i;
            v[i] = (o < 18) ? (f16)offw[((o * CC + c) * 3 + ky) * 3 + kx] : (f16)0.f;
        }
        *(f16x8*)(wA_off + (size_t)(idx * 64 + l) * 8) = v;
    } else if (idx < 108) {
        const int id2 = idx - 36;
        const int mt = id2 & 3, ks = (id2 >> 2) & 1, tap = id2 >> 3;
        const int o = mt * 16 + (l & 15);
        #pragma unroll
        for (int i = 0; i < 8; ++i) {
            const int c = ks * 32 + (l >> 4) * 8 + i;
            v[i] = (f16)dw[(size_t)(o * CC + c) * 9 + tap];
        }
        *(f16x8*)(wA_def + (size_t)(id2 * 64 + l) * 8) = v;
    }
}

// ---------------- main: offset conv (MFMA) + deform conv (MFMA) ----------------
__global__ __launch_bounds__(256, 4) void deform_mfma(
    const f16* __restrict__ xt,
    const f16* __restrict__ wA_off,
    const float* __restrict__ offb,
    const f16* __restrict__ wA_def,
    const float* __restrict__ dbias,
    float* __restrict__ out)
{
    __shared__ f16x8 xs8[1584];        // [3 rows][66 px][64 c] f16, xor-swizzled
    __shared__ float offs[18][64];
    char* xs = (char*)xs8;

    const int tid = threadIdx.x;
    const int bid = blockIdx.x;
    const int b   = bid >> 8;          // 256 blocks per batch
    const int row = (bid >> 1) & 127;
    const int px0 = (bid & 1) * 64;    // half-row

    // ---- stage 3 x_t rows, px range [px0-1, px0+64], zero-padded OOB ----
    for (int i = tid; i < 1584; i += 256) {
        const int r   = i / 528;           // 528 = 66*8 chunks per row
        const int rem = i - r * 528;
        const int sx  = rem >> 3;
        const int cp  = rem & 7;
        const int gy  = row - 1 + r;
        const int gpx = px0 - 1 + sx;
        f16x8 v = {0,0,0,0,0,0,0,0};
        if (gy >= 0 && gy < HH && gpx >= 0 && gpx < WW)
            v = *(const f16x8*)(xt + ((((size_t)b * HH + gy) * WW + gpx) * CC + cp * 8));
        const int byte = ((r * 66 + sx) * 128 + cp * 16) ^ ((sx & 7) << 4);
        *(f16x8*)(xs + byte) = v;
    }
    __syncthreads();

    const int w = tid >> 6;            // wave id = n-tile (16 px)
    const int l = tid & 63;
    const int pxl = w * 16 + (l & 15); // local px 0..63
    const int gpx = px0 + pxl;
    const int cg  = l >> 4;

    // ---- offset conv: [18(pad32) x 64px x 576] via 16x16x32 f16 MFMA ----
    {
        f32x4 oacc0 = {0,0,0,0}, oacc1 = {0,0,0,0};
        #pragma unroll
        for (int ks = 0; ks < 18; ++ks) {
            const int tap = ks >> 1, ky = tap / 3, kx = tap % 3;
            const int chalf = ks & 1;
            const int sx = (l & 15) + w * 16 + kx;
            const int byte = ((ky * 66 + sx) * 128 + chalf * 64 + cg * 16) ^ ((sx & 7) << 4);
            const f16x8 bfrag = *(const f16x8*)(xs + byte);
            const f16x8 a0 = *(const f16x8*)(wA_off + (size_t)((ks * 2 + 0) * 64 + l) * 8);
            const f16x8 a1 = *(const f16x8*)(wA_off + (size_t)((ks * 2 + 1) * 64 + l) * 8);
            oacc0 = __builtin_amdgcn_mfma_f32_16x16x32_f16(a0, bfrag, oacc0, 0, 0, 0);
            oacc1 = __builtin_amdgcn_mfma_f32_16x16x32_f16(a1, bfrag, oacc1, 0, 0, 0);
        }
        #pragma unroll
        for (int reg = 0; reg < 4; ++reg) {
            const int o0 = cg * 4 + reg;           // rows 0..15
            offs[o0][pxl] = oacc0[reg] + offb[o0];
            const int o1 = 16 + o0;                // rows 16..17 valid
            if (o1 < 18) offs[o1][pxl] = oacc1[reg] + offb[o1];
        }
    }
    __syncthreads();

    // ---- deform conv: 9 taps, barrier-free; B-frags gathered to registers ----
    const f16* xb = xt + (size_t)b * HWs * CC;
    f32x4 acc[4] = {{0,0,0,0},{0,0,0,0},{0,0,0,0},{0,0,0,0}};

    for (int tap = 0; tap < 9; ++tap) {
        const int ky = tap / 3, kx = tap - ky * 3;
        const float dy = offs[2 * tap][pxl];
        const float dx = offs[2 * tap + 1][pxl];
        const float py  = (float)(row - 1 + ky) + dy;
        const float pxf = (float)(gpx - 1 + kx) + dx;
        const float y0f = floorf(py), x0f = floorf(pxf);
        const float wy = py - y0f, wx = pxf - x0f;
        const int y0 = (int)y0f, x0i = (int)x0f;
        const int y1 = y0 + 1, x1 = x0i + 1;
        const bool vy0 = (y0 >= 0) & (y0 < HH);
        const bool vy1 = (y1 >= 0) & (y1 < HH);
        const bool vx0 = (x0i >= 0) & (x0i < WW);
        const bool vx1 = (x1 >= 0) & (x1 < WW);
        const float w00 = (1.f - wy) * (1.f - wx) * (float)(vy0 & vx0);
        const float w01 = (1.f - wy) * wx         * (float)(vy0 & vx1);
        const float w10 = wy * (1.f - wx)         * (float)(vy1 & vx0);
        const float w11 = wy * wx                 * (float)(vy1 & vx1);
        const int cy0 = min(max(y0, 0), HH - 1), cy1 = min(max(y1, 0), HH - 1);
        const int cx0 = min(max(x0i, 0), WW - 1), cx1 = min(max(x1, 0), WW - 1);
        const int e00 = (cy0 * WW + cx0) * CC + cg * 8;
        const int e01 = (cy0 * WW + cx1) * CC + cg * 8;
        const int e10 = (cy1 * WW + cx0) * CC + cg * 8;
        const int e11 = (cy1 * WW + cx1) * CC + cg * 8;
        const f16 h00 = (f16)w00, h01 = (f16)w01, h10 = (f16)w10, h11 = (f16)w11;
        const f16x8 W00 = {h00,h00,h00,h00,h00,h00,h00,h00};
        const f16x8 W01 = {h01,h01,h01,h01,h01,h01,h01,h01};
        const f16x8 W10 = {h10,h10,h10,h10,h10,h10,h10,h10};
        const f16x8 W11 = {h11,h11,h11,h11,h11,h11,h11,h11};

        #pragma unroll
        for (int ks = 0; ks < 2; ++ks) {
            const int co = ks * 32;
            const f16x8 p00 = *(const f16x8*)(xb + e00 + co);
            const f16x8 p01 = *(const f16x8*)(xb + e01 + co);
            const f16x8 p10 = *(const f16x8*)(xb + e10 + co);
            const f16x8 p11 = *(const f16x8*)(xb + e11 + co);
            const f16x8 bfrag = p00 * W00 + p01 * W01 + p10 * W10 + p11 * W11;
            #pragma unroll
            for (int mt = 0; mt < 4; ++mt) {
                const f16x8 a = *(const f16x8*)(wA_def +
                                 (size_t)(((tap * 2 + ks) * 4 + mt) * 64 + l) * 8);
                acc[mt] = __builtin_amdgcn_mfma_f32_16x16x32_f16(a, bfrag, acc[mt], 0, 0, 0);
            }
        }
    }

    // ---- epilogue ----
    #pragma unroll
    for (int mt = 0; mt < 4; ++mt) {
        #pragma unroll
        for (int reg = 0; reg < 4; ++reg) {
            const int o = mt * 16 + cg * 4 + reg;
            out[(((size_t)b * OO + o) * HH + row) * WW + gpx] = acc[mt][reg] + dbias[o];
        }
    }
}

// ======================= round-1 fallback (small d_ws) =======================
__global__ void transpose_w(const float* __restrict__ dw, float* __restrict__ wt) {
    int t = blockIdx.x * 256 + threadIdx.x;
    if (t >= OO * CC * 9) return;
    int o = t & 63;
    int c = (t >> 6) & 63;
    int k = t >> 12;
    wt[t] = dw[(o * CC + c) * 9 + k];
}

__global__ __launch_bounds__(256) void deform_kernel(
    const float* __restrict__ x, const float* __restrict__ offw,
    const float* __restrict__ offb, const float* __restrict__ dw,
    const float* __restrict__ dbias, const float* __restrict__ wt,
    int use_wt, float* __restrict__ out)
{
    __shared__ float offs[18][128];
    __shared__ float samp[CC][128];
    __shared__ float wlds[CC][68];

    const int tid = threadIdx.x;
    const int bid = blockIdx.x;
    const int row = bid & 127;
    const int b   = bid >> 7;
    const float* xb0 = x + (size_t)b * CC * HWs;
    {
        const int wv  = tid >> 6;
        const int ln1 = tid & 63;
        const int col = ln1 + ((wv & 1) << 6);
        const int chb = __builtin_amdgcn_readfirstlane((wv >> 1) * 9);
        float acc9[9];
        #pragma unroll
        for (int j = 0; j < 9; ++j) acc9[j] = offb[chb + j];
        const bool rok0 = (row > 0), rok2 = (row < HH - 1);
        const bool cok0 = (col > 0), cok2 = (col < WW - 1);
        const int r0 = (row - 1) * WW, r1 = row * WW, r2 = (row + 1) * WW;
        for (int c = 0; c < CC; ++c) {
            const float* xc = xb0 + c * HWs;
            float xv[9];
            xv[0] = (rok0 & cok0) ? xc[r0 + col - 1] : 0.f;
            xv[1] =  rok0         ? xc[r0 + col    ] : 0.f;
            xv[2] = (rok0 & cok2) ? xc[r0 + col + 1] : 0.f;
            xv[3] =  cok0         ? xc[r1 + col - 1] : 0.f;
            xv[4] =                 xc[r1 + col    ];
            xv[5] =  cok2         ? xc[r1 + col + 1] : 0.f;
            xv[6] = (rok2 & cok0) ? xc[r2 + col - 1] : 0.f;
            xv[7] =  rok2         ? xc[r2 + col    ] : 0.f;
            xv[8] = (rok2 & cok2) ? xc[r2 + col + 1] : 0.f;
            const float* wp = offw + (size_t)chb * (CC * 9) + c * 9;
            #pragma unroll
            for (int j = 0; j < 9; ++j)
                #pragma unroll
                for (int kk = 0; kk < 9; ++kk)
                    acc9[j] = fmaf(xv[kk], wp[j * (CC * 9) + kk], acc9[j]);
        }
        #pragma unroll
        for (int j = 0; j < 9; ++j) offs[chb + j][col] = acc9[j];
    }
    __syncthreads();
    const int ln    = tid & 63;
    const int obase = (tid >> 6) * 16;
    const int gpx   = tid & 127;
    const int gc0   = tid >> 7;
    float acc0[16], acc1[16];
    #pragma unroll
    for (int j = 0; j < 16; ++j) { acc0[j] = 0.f; acc1[j] = 0.f; }
    for (int k = 0; k < 9; ++k) {
        if (use_wt) {
            const float* s = wt + k * (CC * OO);
            #pragma unroll
            for (int i = 0; i < 16; ++i) {
                int e = tid + i * 256;
                wlds[e >> 6][e & 63] = s[e];
            }
        } else {
            #pragma unroll
            for (int i = 0; i < 16; ++i) {
                int e = tid + i * 256;
                wlds[e & 63][e >> 6] = dw[((e >> 6) * CC + (e & 63)) * 9 + k];
            }
        }
        const float dy = offs[2 * k    ][gpx];
        const float dx = offs[2 * k + 1][gpx];
        const float py  = (float)(row - 1 + k / 3) + dy;
        const float pxf = (float)(gpx - 1 + k % 3) + dx;
        const float y0f = floorf(py), x0f = floorf(pxf);
        const float wy = py - y0f, wx = pxf - x0f;
        const int y0 = (int)y0f, x0 = (int)x0f;
        const int y1 = y0 + 1,  x1 = x0 + 1;
        const bool vy0 = (y0 >= 0) & (y0 < HH);
        const bool vy1 = (y1 >= 0) & (y1 < HH);
        const bool vx0 = (x0 >= 0) & (x0 < WW);
        const bool vx1 = (x1 >= 0) & (x1 < WW);
        const float w00 = (1.f - wy) * (1.f - wx) * (float)(vy0 & vx0);
        const float w01 = (1.f - wy) * wx         * (float)(vy0 & vx1);
        const float w10 = wy * (1.f - wx)         * (float)(vy1 & vx0);
        const float w11 = wy * wx                 * (float)(vy1 & vx1);
        const int cy0 = min(max(y0, 0), HH - 1), cy1 = min(max(y1, 0), HH - 1);
        const int cx0 = min(max(x0, 0), WW - 1), cx1 = min(max(x1, 0), WW - 1);
        const int a00 = cy0 * WW + cx0, a01 = cy0 * WW + cx1;
        const int a10 = cy1 * WW + cx0, a11 = cy1 * WW + cx1;
        const float* xc = xb0 + gc0 * HWs;
        #pragma unroll 8
        for (int cc = 0; cc < 32; ++cc) {
            const float* p = xc + (size_t)(cc * 2) * HWs;
            float v = w00 * p[a00] + w01 * p[a01] + w10 * p[a10] + w11 * p[a11];
            samp[gc0 + 2 * cc][gpx] = v;
        }
        __syncthreads();
        #pragma unroll 4
        for (int c = 0; c < CC; ++c) {
            const float s0 = samp[c][ln];
            const float s1 = samp[c][ln + 64];
            const float4* wr = (const float4*)&wlds[c][obase];
            float wv16[16];
            *(float4*)&wv16[0]  = wr[0];
            *(float4*)&wv16[4]  = wr[1];
            *(float4*)&wv16[8]  = wr[2];
            *(float4*)&wv16[12] = wr[3];
            #pragma unroll
            for (int j = 0; j < 16; ++j) {
                acc0[j] = fmaf(wv16[j], s0, acc0[j]);
                acc1[j] = fmaf(wv16[j], s1, acc1[j]);
            }
        }
        __syncthreads();
    }
    #pragma unroll
    for (int j = 0; j < 16; ++j) {
        const float bias = dbias[obase + j];
        float* op = out + ((size_t)(b * OO + obase + j) * HH + row) * WW;
        op[ln]      = acc0[j] + bias;
        op[ln + 64] = acc1[j] + bias;
    }
}

extern "C" void kernel_launch(void* const* d_in, const int* in_sizes, int n_in,
                              void* d_out, int out_size, void* d_ws, size_t ws_size,
                              hipStream_t stream) {
    const float* x     = (const float*)d_in[0];
    const float* offw  = (const float*)d_in[1];
    const float* offb  = (const float*)d_in[2];
    const float* dw    = (const float*)d_in[3];
    const float* dbias = (const float*)d_in[4];
    float* out = (float*)d_out;

    const size_t XT_BYTES    = (size_t)BB * HH * WW * CC * sizeof(f16);   // 8 MiB
    const size_t WAOFF_BYTES = 36 * 64 * 8 * sizeof(f16);
    const size_t WADEF_BYTES = 72 * 64 * 8 * sizeof(f16);
    const size_t NEED = XT_BYTES + WAOFF_BYTES + WADEF_BYTES;

    if (ws_size >= NEED) {
        f16* xt     = (f16*)d_ws;
        f16* wa_off = (f16*)((char*)d_ws + XT_BYTES);
        f16* wa_def = (f16*)((char*)d_ws + XT_BYTES + WAOFF_BYTES);
        transpose_x<<<BB * HH, 128, 0, stream>>>(x, xt);
        prep_w<<<27, 256, 0, stream>>>(offw, dw, wa_off, wa_def);
        deform_mfma<<<BB * HH * 2, 256, 0, stream>>>(xt, wa_off, offb, wa_def, dbias, out);
    } else {
        float* wtp = (float*)d_ws;
        const int use_wt = (ws_size >= (size_t)(OO * CC * 9 * sizeof(float))) ? 1 : 0;
        if (use_wt)
            transpose_w<<<(OO * CC * 9 + 255) / 256, 256, 0, stream>>>(dw, wtp);
        deform_kernel<<<BB * HH, 256, 0, stream>>>(x, offw, offb, dw, dbias, wtp, use_wt, out);
    }
}